// Round 5
// baseline (142.362 us; speedup 1.0000x reference)
//
#include <hip/hip_runtime.h>

#define D_MODEL 1024
#define KK 64
#define BSZ 16

// ---------------------------------------------------------------------------
// Prep kernel, grid (16, 17):
//  y < 16 : transpose tile — MpT[b][d0+d][j] = Mp[b][j][d0+d], d0 = y*64,
//           via a 64x65 LDS tile (odd stride -> bank-conflict-free-ish).
//  y == 16: P12 for batch b: 4 threads per row, each reduces 256 d.
//           P1[r][c] = sum_d Mp[r,d]*W[c,d]      -> P12[r*3+c]
//           P2[r][c] = sum_d Mp[r,d]*W[c,1024+d] -> P12[3072 + r*3+c]
// ---------------------------------------------------------------------------
__global__ __launch_bounds__(256) void prep_kernel(
    const float* __restrict__ Mp, const float* __restrict__ W,
    float* __restrict__ MpT, float* __restrict__ P12)
{
    const int b = blockIdx.x;
    const int y = blockIdx.y;
    const int t = threadIdx.x;

    if (y < 16) {
        __shared__ float tile[64 * 65];
        const int d0 = y * 64;
        const float* __restrict__ src = Mp + (size_t)b * (KK * D_MODEL);
#pragma unroll
        for (int p = 0; p < 4; ++p) {
            const int idx = p * 256 + t;      // 0..1023
            const int j   = idx >> 4;         // 0..63
            const int c4  = (idx & 15) * 4;   // 0..60
            const float4 v = *reinterpret_cast<const float4*>(src + j * D_MODEL + d0 + c4);
            float* dst = &tile[j * 65 + c4];
            dst[0] = v.x; dst[1] = v.y; dst[2] = v.z; dst[3] = v.w;
        }
        __syncthreads();
        float* __restrict__ dstb = MpT + (size_t)b * (KK * D_MODEL) + (size_t)d0 * KK;
#pragma unroll
        for (int p = 0; p < 4; ++p) {
            const int idx = p * 256 + t;
            const int d   = idx >> 4;         // 0..63
            const int j4  = (idx & 15) * 4;   // 0..60
            float4 v;
            v.x = tile[(j4 + 0) * 65 + d];
            v.y = tile[(j4 + 1) * 65 + d];
            v.z = tile[(j4 + 2) * 65 + d];
            v.w = tile[(j4 + 3) * 65 + d];
            *reinterpret_cast<float4*>(dstb + d * KK + j4) = v;  // 256B rows, coalesced
        }
    } else {
        // P12 for batch b: row = b*64 + (t>>2); quarter q = t&3 covers d in [q*256, q*256+256)
        __shared__ float part[64][6][4];
        const int rl = t >> 2;                // local row 0..63
        const int q  = t & 3;
        const float* __restrict__ rp = Mp + ((size_t)(b * KK + rl)) * D_MODEL + q * 256;
        float s[6] = {0.f, 0.f, 0.f, 0.f, 0.f, 0.f};
        for (int kk = 0; kk < 64; ++kk) {
            const float4 m = *reinterpret_cast<const float4*>(rp + kk * 4);
#pragma unroll
            for (int c = 0; c < 3; ++c) {
                const float4 w1 = *reinterpret_cast<const float4*>(W + c * 4096 + q * 256 + kk * 4);
                const float4 w2 = *reinterpret_cast<const float4*>(W + c * 4096 + 1024 + q * 256 + kk * 4);
                s[c]     += m.x * w1.x + m.y * w1.y + m.z * w1.z + m.w * w1.w;
                s[3 + c] += m.x * w2.x + m.y * w2.y + m.z * w2.z + m.w * w2.w;
            }
        }
#pragma unroll
        for (int u = 0; u < 6; ++u) part[rl][u][q] = s[u];
        __syncthreads();
        if (t < 128) {
            const int rr   = t >> 1;          // 0..63
            const int half = t & 1;           // 0 = P1, 1 = P2
#pragma unroll
            for (int c = 0; c < 3; ++c) {
                const float v = part[rr][half * 3 + c][0] + part[rr][half * 3 + c][1]
                              + part[rr][half * 3 + c][2] + part[rr][half * 3 + c][3];
                P12[(half ? 3072 : 0) + (b * KK + rr) * 3 + c] = v;
            }
        }
    }
}

// ---------------------------------------------------------------------------
// Pair kernel: grid (16, 32); block = (b, i0=2y, i0+1); 4 waves split d.
// lane = j. mj from MpT (coalesced 256B global loads, L2-hot); mi and W are
// wave-uniform -> scalar loads. No LDS in the main loop.
//   out[b,i,j,c] = P1[j,c] + P2[i,c] + sum_d |mi-mj|*W3[c,d] + mi*mj*W4[c,d]
// ---------------------------------------------------------------------------
__global__ __launch_bounds__(256) void pair_kernel(
    const float* __restrict__ Mp, const float* __restrict__ W,
    const float* __restrict__ MpT, const float* __restrict__ P12,
    float* __restrict__ out)
{
    __shared__ float red[4][2][3][64];   // 6 KB

    const int b    = blockIdx.x;          // 0..15
    const int i0   = blockIdx.y * 2;      // 0..62
    const int lane = threadIdx.x & 63;    // = j
    const int wid  = threadIdx.x >> 6;    // 0..3
    const int uwid = __builtin_amdgcn_readfirstlane(wid);

    const int dbase = uwid * 256;
    const float* __restrict__ mjp  = MpT + (size_t)b * (KK * D_MODEL) + (size_t)dbase * KK + lane;
    const float* __restrict__ mi0p = Mp + ((size_t)(b * KK + i0)) * D_MODEL + dbase;
    const float* __restrict__ mi1p = mi0p + D_MODEL;
    const float* __restrict__ w3b  = W + 2048 + dbase;   // + c*4096 + k
    const float* __restrict__ w4b  = W + 3072 + dbase;

    float a00 = 0.f, a01 = 0.f, a02 = 0.f;
    float a10 = 0.f, a11 = 0.f, a12 = 0.f;

#pragma unroll 8
    for (int k = 0; k < 256; ++k) {
        const float mj  = mjp[k * KK];        // coalesced, L2-hot
        const float mi0 = mi0p[k];            // wave-uniform -> s_load
        const float mi1 = mi1p[k];
        const float u0 = w3b[k], u1 = w3b[4096 + k], u2 = w3b[8192 + k];
        const float v0 = w4b[k], v1 = w4b[4096 + k], v2 = w4b[8192 + k];

        const float d0 = mi0 - mj;
        const float p0 = mi0 * mj;
        a00 = fmaf(fabsf(d0), u0, a00);  a00 = fmaf(p0, v0, a00);
        a01 = fmaf(fabsf(d0), u1, a01);  a01 = fmaf(p0, v1, a01);
        a02 = fmaf(fabsf(d0), u2, a02);  a02 = fmaf(p0, v2, a02);

        const float d1 = mi1 - mj;
        const float p1 = mi1 * mj;
        a10 = fmaf(fabsf(d1), u0, a10);  a10 = fmaf(p1, v0, a10);
        a11 = fmaf(fabsf(d1), u1, a11);  a11 = fmaf(p1, v1, a11);
        a12 = fmaf(fabsf(d1), u2, a12);  a12 = fmaf(p1, v2, a12);
    }

    red[wid][0][0][lane] = a00;  red[wid][0][1][lane] = a01;  red[wid][0][2][lane] = a02;
    red[wid][1][0][lane] = a10;  red[wid][1][1][lane] = a11;  red[wid][1][2][lane] = a12;
    __syncthreads();

    if (wid < 2) {
        const int i = i0 + wid;
        const float p2c0 = P12[3072 + (b * KK + i) * 3 + 0];
        const float p2c1 = P12[3072 + (b * KK + i) * 3 + 1];
        const float p2c2 = P12[3072 + (b * KK + i) * 3 + 2];
        float* __restrict__ orow = out + (((size_t)(b * KK + i)) * KK + lane) * 3;
#pragma unroll
        for (int c = 0; c < 3; ++c) {
            const float s = red[0][wid][c][lane] + red[1][wid][c][lane]
                          + red[2][wid][c][lane] + red[3][wid][c][lane];
            const float p2 = (c == 0) ? p2c0 : (c == 1) ? p2c1 : p2c2;
            orow[c] = s + P12[(b * KK + lane) * 3 + c] + p2;
        }
    }
}

extern "C" void kernel_launch(void* const* d_in, const int* in_sizes, int n_in,
                              void* d_out, int out_size, void* d_ws, size_t ws_size,
                              hipStream_t stream)
{
    const float* Mp = (const float*)d_in[0];   // (16, 64, 1024) f32
    // d_in[1] = mask_p: unused by the reference (all-ones, never applied)
    const float* W  = (const float*)d_in[2];   // (3, 4096) f32
    float* out = (float*)d_out;                // (16, 64, 64, 3) f32

    float* MpT = (float*)d_ws;                 // 16*1024*64 floats = 4 MB
    float* P12 = MpT + (size_t)BSZ * KK * D_MODEL;  // 6144 floats

    prep_kernel<<<dim3(BSZ, 17), 256, 0, stream>>>(Mp, W, MpT, P12);
    pair_kernel<<<dim3(BSZ, 32), 256, 0, stream>>>(Mp, W, MpT, P12, out);
}

// Round 7
// 100.862 us; speedup vs baseline: 1.4115x; 1.4115x over previous
//
#include <hip/hip_runtime.h>

#define D_MODEL 1024
#define KK 64
#define BSZ 16

// ws layout (floats):
//   MpT2  [16][256][64][4]  = 1,048,576 floats (4 MB)   — float4 tile (d/4, j)
//   Ppart [16][16][64][6]   =    98,304 floats (384 KB) — per-d-tile P1/P2 partials
#define MPT2_F4_PER_B (256 * 64)
#define PPART_OFF (BSZ * 256 * 64 * 4)

// ---------------------------------------------------------------------------
// prep2: grid (16 b, 16 d-tiles), 256 threads.
//  * loads Mp tile [64 j][64 d] into LDS (padded stride 65)
//  * writes MpT2[b][(d0+d)/4][j] = float4{Mp[b][j][d..d+3]}  (coalesced over j)
//  * computes P partials for this d-tile:
//      Ppart[b][dt][j][c]   = sum_{d in tile} Mp[j,d] * W[c, d]        (P1)
//      Ppart[b][dt][j][3+c] = sum_{d in tile} Mp[j,d] * W[c, 1024+d]   (P2)
// ---------------------------------------------------------------------------
__global__ __launch_bounds__(256) void prep2(
    const float* __restrict__ Mp, const float* __restrict__ W,
    float* __restrict__ MpT2, float* __restrict__ Ppart)
{
    __shared__ float tile[64 * 65];
    __shared__ float Wt[6 * 64];
    __shared__ float part[64][6][4];

    const int b  = blockIdx.x;
    const int dt = blockIdx.y;
    const int t  = threadIdx.x;
    const int d0 = dt * 64;

    const float* __restrict__ src = Mp + (size_t)b * KK * D_MODEL;
#pragma unroll
    for (int p = 0; p < 4; ++p) {
        const int idx = p * 256 + t;          // 0..1023
        const int j   = idx >> 4;             // 0..63
        const int c4  = (idx & 15) * 4;       // 0..60
        const float4 v = *reinterpret_cast<const float4*>(src + j * D_MODEL + d0 + c4);
        float* dst = &tile[j * 65 + c4];
        dst[0] = v.x; dst[1] = v.y; dst[2] = v.z; dst[3] = v.w;
    }
    // stage W1/W2 slice: Wt[cc][d]  (384 entries, block has 256 threads -> stride loop)
    for (int u = t; u < 384; u += 256) {
        const int cc = u >> 6, d = u & 63;
        Wt[cc * 64 + d] = W[(cc < 3 ? cc : cc - 3) * 4096 + (cc < 3 ? 0 : 1024) + d0 + d];
    }
    __syncthreads();

    // transpose-write MpT2 (float4 per (d4, j), coalesced over j)
    float4* __restrict__ dstb =
        reinterpret_cast<float4*>(MpT2) + (size_t)b * MPT2_F4_PER_B + (d0 >> 2) * 64;
#pragma unroll
    for (int p = 0; p < 4; ++p) {
        const int idx = p * 256 + t;
        const int d4l = idx >> 6;             // 0..15
        const int j   = idx & 63;
        const float* s = &tile[j * 65 + d4l * 4];
        float4 v; v.x = s[0]; v.y = s[1]; v.z = s[2]; v.w = s[3];
        dstb[d4l * 64 + j] = v;
    }

    // P partials: thread (j = t>>2, q = t&3) reduces its 16-d slice
    {
        const int j = t >> 2, q = t & 3;
        float s[6] = {0.f, 0.f, 0.f, 0.f, 0.f, 0.f};
#pragma unroll
        for (int dd = 0; dd < 16; ++dd) {
            const int d   = q * 16 + dd;
            const float m = tile[j * 65 + d];
#pragma unroll
            for (int cc = 0; cc < 6; ++cc) s[cc] = fmaf(m, Wt[cc * 64 + d], s[cc]);
        }
#pragma unroll
        for (int cc = 0; cc < 6; ++cc) part[j][cc][q] = s[cc];
    }
    __syncthreads();

    // write Ppart: 64 j x 6 cc = 384 entries, stride loop over 256 threads
    for (int u = t; u < 384; u += 256) {
        const int j = u / 6, cc = u % 6;
        const float v = part[j][cc][0] + part[j][cc][1] + part[j][cc][2] + part[j][cc][3];
        Ppart[((size_t)(b * 16 + dt) * 64 + j) * 6 + cc] = v;
    }
}

// ---------------------------------------------------------------------------
// pair2: grid (16 b, 32 i-tiles), 256 threads; wave = d-quarter, lane = j,
// 2 i-rows per block. Per 4 k's: ONE coalesced float4 mj load + 8 uniform
// float4 loads (mi0, mi1, W3[c], W4[c]) that the compiler can scalarize.
//   out[b,i,j,c] = P1[j,c] + P2[i,c] + sum_d |mi-mj|*W3[c,d] + mi*mj*W4[c,d]
// ---------------------------------------------------------------------------
__global__ __launch_bounds__(256) void pair2(
    const float* __restrict__ Mp, const float* __restrict__ W,
    const float* __restrict__ MpT2, const float* __restrict__ Ppart,
    float* __restrict__ out)
{
    __shared__ float red[4][2][3][64];

    const int b    = blockIdx.x;
    const int i0   = blockIdx.y * 2;
    const int lane = threadIdx.x & 63;        // = j
    const int wid  = threadIdx.x >> 6;
    const int uwid = __builtin_amdgcn_readfirstlane(wid);

    const float4* __restrict__ mjp =
        reinterpret_cast<const float4*>(MpT2) + (size_t)b * MPT2_F4_PER_B + uwid * 64 * 64 + lane;
    const float* __restrict__ mi0p = Mp + ((size_t)(b * KK + i0)) * D_MODEL + uwid * 256;
    const float* __restrict__ mi1p = mi0p + D_MODEL;
    const float* __restrict__ w3b  = W + 2048 + uwid * 256;
    const float* __restrict__ w4b  = W + 3072 + uwid * 256;

    float a00 = 0.f, a01 = 0.f, a02 = 0.f;
    float a10 = 0.f, a11 = 0.f, a12 = 0.f;

#pragma unroll 4
    for (int k4 = 0; k4 < 64; ++k4) {
        const float4 mj = mjp[k4 * 64];                                     // coalesced
        const float4 m0 = *reinterpret_cast<const float4*>(mi0p + k4 * 4);  // uniform
        const float4 m1 = *reinterpret_cast<const float4*>(mi1p + k4 * 4);  // uniform
        const float4 u0 = *reinterpret_cast<const float4*>(w3b + k4 * 4);
        const float4 u1 = *reinterpret_cast<const float4*>(w3b + 4096 + k4 * 4);
        const float4 u2 = *reinterpret_cast<const float4*>(w3b + 8192 + k4 * 4);
        const float4 v0 = *reinterpret_cast<const float4*>(w4b + k4 * 4);
        const float4 v1 = *reinterpret_cast<const float4*>(w4b + 4096 + k4 * 4);
        const float4 v2 = *reinterpret_cast<const float4*>(w4b + 8192 + k4 * 4);

#define EL(E) {                                                        \
        const float df0 = fabsf(m0.E - mj.E), pr0 = m0.E * mj.E;       \
        a00 = fmaf(df0, u0.E, a00);  a00 = fmaf(pr0, v0.E, a00);       \
        a01 = fmaf(df0, u1.E, a01);  a01 = fmaf(pr0, v1.E, a01);       \
        a02 = fmaf(df0, u2.E, a02);  a02 = fmaf(pr0, v2.E, a02);       \
        const float df1 = fabsf(m1.E - mj.E), pr1 = m1.E * mj.E;       \
        a10 = fmaf(df1, u0.E, a10);  a10 = fmaf(pr1, v0.E, a10);       \
        a11 = fmaf(df1, u1.E, a11);  a11 = fmaf(pr1, v1.E, a11);       \
        a12 = fmaf(df1, u2.E, a12);  a12 = fmaf(pr1, v2.E, a12); }
        EL(x) EL(y) EL(z) EL(w)
#undef EL
    }

    red[wid][0][0][lane] = a00;  red[wid][0][1][lane] = a01;  red[wid][0][2][lane] = a02;
    red[wid][1][0][lane] = a10;  red[wid][1][1][lane] = a11;  red[wid][1][2][lane] = a12;
    __syncthreads();

    if (wid < 2) {
        const int i = i0 + wid;
        const float* __restrict__ Pb = Ppart + (size_t)b * 16 * 64 * 6;
        float p1[3] = {0.f, 0.f, 0.f}, p2[3] = {0.f, 0.f, 0.f};
#pragma unroll
        for (int dt = 0; dt < 16; ++dt) {
            const float* q1 = Pb + (dt * 64 + lane) * 6;       // P1[j = lane]
            const float* q2 = Pb + (dt * 64 + i) * 6 + 3;      // P2[i]
#pragma unroll
            for (int c = 0; c < 3; ++c) { p1[c] += q1[c]; p2[c] += q2[c]; }
        }
        float* __restrict__ orow = out + (((size_t)(b * KK + i)) * KK + lane) * 3;
#pragma unroll
        for (int c = 0; c < 3; ++c) {
            orow[c] = red[0][wid][c][lane] + red[1][wid][c][lane]
                    + red[2][wid][c][lane] + red[3][wid][c][lane]
                    + p1[c] + p2[c];
        }
    }
}

extern "C" void kernel_launch(void* const* d_in, const int* in_sizes, int n_in,
                              void* d_out, int out_size, void* d_ws, size_t ws_size,
                              hipStream_t stream)
{
    const float* Mp = (const float*)d_in[0];   // (16, 64, 1024) f32
    // d_in[1] = mask_p: unused by the reference (all-ones, never applied)
    const float* W  = (const float*)d_in[2];   // (3, 4096) f32
    float* out = (float*)d_out;                // (16, 64, 64, 3) f32

    float* MpT2  = (float*)d_ws;
    float* Ppart = MpT2 + PPART_OFF;

    prep2<<<dim3(BSZ, 16), 256, 0, stream>>>(Mp, W, MpT2, Ppart);
    pair2<<<dim3(BSZ, 32), 256, 0, stream>>>(Mp, W, MpT2, Ppart, out);
}

// Round 9
// 83.366 us; speedup vs baseline: 1.7077x; 1.2099x over previous
//
#include <hip/hip_runtime.h>

#define D_MODEL 1024
#define KK 64
#define BSZ 16

// ws layout (floats):
//   MpT2  [16][256][64][4]  = 1,048,576 floats (4 MB)   — float4 tile (d/4, j)
//   Ppart [16][16][6][64]   =    98,304 floats (384 KB) — per-d-tile P partials
//     cc<3: P1 partial (c=cc) over j; cc>=3: P2 partial (c=cc-3) over row index
#define MPT2_F4_PER_B (256 * 64)
#define PPART_OFF (BSZ * 256 * 64 * 4)

// ---------------------------------------------------------------------------
// prep2: grid (16 b, 16 d-tiles), 256 threads.
//  * loads Mp tile [64 j][64 d] into LDS (padded stride 65)
//  * writes MpT2[b][(d0+d)/4][j] = float4{Mp[b][j][d..d+3]}  (coalesced over j)
//  * Ppart[b][dt][cc][j] = sum_{d in tile} Mp[j,d] * W[cc<3? cc : cc-3, (cc<3?0:1024)+d]
// ---------------------------------------------------------------------------
__global__ __launch_bounds__(256) void prep2(
    const float* __restrict__ Mp, const float* __restrict__ W,
    float* __restrict__ MpT2, float* __restrict__ Ppart)
{
    __shared__ float tile[64 * 65];
    __shared__ float Wt[6 * 64];
    __shared__ float part[64][6][4];

    const int b  = blockIdx.x;
    const int dt = blockIdx.y;
    const int t  = threadIdx.x;
    const int d0 = dt * 64;

    const float* __restrict__ src = Mp + (size_t)b * KK * D_MODEL;
#pragma unroll
    for (int p = 0; p < 4; ++p) {
        const int idx = p * 256 + t;          // 0..1023
        const int j   = idx >> 4;             // 0..63
        const int c4  = (idx & 15) * 4;       // 0..60
        const float4 v = *reinterpret_cast<const float4*>(src + j * D_MODEL + d0 + c4);
        float* dst = &tile[j * 65 + c4];
        dst[0] = v.x; dst[1] = v.y; dst[2] = v.z; dst[3] = v.w;
    }
    for (int u = t; u < 384; u += 256) {      // stage W1/W2 slice: Wt[cc][d]
        const int cc = u >> 6, d = u & 63;
        Wt[cc * 64 + d] = W[(cc < 3 ? cc : cc - 3) * 4096 + (cc < 3 ? 0 : 1024) + d0 + d];
    }
    __syncthreads();

    // transpose-write MpT2 (float4 per (d4, j), coalesced over j)
    float4* __restrict__ dstb =
        reinterpret_cast<float4*>(MpT2) + (size_t)b * MPT2_F4_PER_B + (d0 >> 2) * 64;
#pragma unroll
    for (int p = 0; p < 4; ++p) {
        const int idx = p * 256 + t;
        const int d4l = idx >> 6;             // 0..15
        const int j   = idx & 63;
        const float* s = &tile[j * 65 + d4l * 4];
        float4 v; v.x = s[0]; v.y = s[1]; v.z = s[2]; v.w = s[3];
        dstb[d4l * 64 + j] = v;
    }

    // P partials: thread (j = t>>2, q = t&3) reduces its 16-d slice
    {
        const int j = t >> 2, q = t & 3;
        float s[6] = {0.f, 0.f, 0.f, 0.f, 0.f, 0.f};
#pragma unroll
        for (int dd = 0; dd < 16; ++dd) {
            const int d   = q * 16 + dd;
            const float m = tile[j * 65 + d];
#pragma unroll
            for (int cc = 0; cc < 6; ++cc) s[cc] = fmaf(m, Wt[cc * 64 + d], s[cc]);
        }
#pragma unroll
        for (int cc = 0; cc < 6; ++cc) part[j][cc][q] = s[cc];
    }
    __syncthreads();

    // write Ppart[b][dt][cc][j]: 6 cc x 64 j = 384 entries, stride loop
    for (int u = t; u < 384; u += 256) {
        const int cc = u >> 6, j = u & 63;
        const float v = part[j][cc][0] + part[j][cc][1] + part[j][cc][2] + part[j][cc][3];
        Ppart[((size_t)(b * 16 + dt) * 6 + cc) * 64 + j] = v;
    }
}

// ---------------------------------------------------------------------------
// pair3: grid (16 b, 16 itiles), 512 threads (8 waves). Block covers 4 i-rows;
// wave uwid owns d-slice [uwid*128, uwid*128+128); lane = j.
// W3/W4 (24 KB) and the 4 mi rows (16 KB) staged in LDS, read via
// uniform-address ds_read_b128 (broadcast). Per k4: 1 coalesced mj float4
// (global, L2-hot) + 10 LDS reads feed 128 FMA-class ops.
//   out[b,i,j,c] = P1[j,c] + P2[i,c] + sum_d |mi-mj|*W3[c,d] + mi*mj*W4[c,d]
// ---------------------------------------------------------------------------
__global__ __launch_bounds__(512) void pair3(
    const float* __restrict__ Mp, const float* __restrict__ W,
    const float* __restrict__ MpT2, const float* __restrict__ Ppart,
    float* __restrict__ out)
{
    __shared__ float Wlds[6 * 1024];     // 24 KB
    __shared__ float Milds[4 * 1024];    // 16 KB
    __shared__ float red[8][4][3][64];   // 6 KB

    const int b    = blockIdx.x;          // 0..15  (linear%8 = b%8 -> XCD locality)
    const int i0   = blockIdx.y * 4;      // 0..60
    const int t    = threadIdx.x;
    const int lane = t & 63;              // = j
    const int wid  = t >> 6;              // 0..7
    const int uwid = __builtin_amdgcn_readfirstlane(wid);

    // stage W3/W4: Wlds[cc*1024 + d]; cc<3 -> W3 c=cc, cc>=3 -> W4 c=cc-3
    for (int u = t; u < 1536; u += 512) {            // float4 granularity
        const int cc = u >> 8;                       // 0..5
        const int d4 = u & 255;
        const float4 v = *reinterpret_cast<const float4*>(
            W + (cc < 3 ? cc : cc - 3) * 4096 + (cc < 3 ? 2048 : 3072) + d4 * 4);
        *reinterpret_cast<float4*>(&Wlds[cc * 1024 + d4 * 4]) = v;
    }
    // stage mi rows i0..i0+3
    for (int u = t; u < 1024; u += 512) {
        const int r  = u >> 8;
        const int d4 = u & 255;
        const float4 v = *reinterpret_cast<const float4*>(
            Mp + ((size_t)(b * KK + i0 + r)) * D_MODEL + d4 * 4);
        *reinterpret_cast<float4*>(&Milds[r * 1024 + d4 * 4]) = v;
    }
    __syncthreads();

    const float4* __restrict__ mjp = reinterpret_cast<const float4*>(MpT2)
        + (size_t)b * MPT2_F4_PER_B + uwid * 32 * 64 + lane;
    const int db = uwid * 128;            // this wave's d base (floats)

    float a0c0 = 0.f, a0c1 = 0.f, a0c2 = 0.f;
    float a1c0 = 0.f, a1c1 = 0.f, a1c2 = 0.f;
    float a2c0 = 0.f, a2c1 = 0.f, a2c2 = 0.f;
    float a3c0 = 0.f, a3c1 = 0.f, a3c2 = 0.f;

#pragma unroll 4
    for (int k4 = 0; k4 < 32; ++k4) {
        const float4 mj = mjp[k4 * 64];   // coalesced, L2-hot
        const int dd = db + k4 * 4;
        const float4 m0 = *reinterpret_cast<const float4*>(&Milds[dd]);
        const float4 m1 = *reinterpret_cast<const float4*>(&Milds[1024 + dd]);
        const float4 m2 = *reinterpret_cast<const float4*>(&Milds[2048 + dd]);
        const float4 m3 = *reinterpret_cast<const float4*>(&Milds[3072 + dd]);
        const float4 u0 = *reinterpret_cast<const float4*>(&Wlds[dd]);
        const float4 u1 = *reinterpret_cast<const float4*>(&Wlds[1024 + dd]);
        const float4 u2 = *reinterpret_cast<const float4*>(&Wlds[2048 + dd]);
        const float4 v0 = *reinterpret_cast<const float4*>(&Wlds[3072 + dd]);
        const float4 v1 = *reinterpret_cast<const float4*>(&Wlds[4096 + dd]);
        const float4 v2 = *reinterpret_cast<const float4*>(&Wlds[5120 + dd]);

#define ROWE(M, A0, A1, A2, E) {                                   \
        const float df = fabsf(M.E - mj.E);                        \
        const float pr = M.E * mj.E;                               \
        A0 = fmaf(df, u0.E, A0);  A0 = fmaf(pr, v0.E, A0);         \
        A1 = fmaf(df, u1.E, A1);  A1 = fmaf(pr, v1.E, A1);         \
        A2 = fmaf(df, u2.E, A2);  A2 = fmaf(pr, v2.E, A2); }
#define ALLR(E) ROWE(m0, a0c0, a0c1, a0c2, E) ROWE(m1, a1c0, a1c1, a1c2, E) \
                ROWE(m2, a2c0, a2c1, a2c2, E) ROWE(m3, a3c0, a3c1, a3c2, E)
        ALLR(x) ALLR(y) ALLR(z) ALLR(w)
#undef ALLR
#undef ROWE
    }

    red[wid][0][0][lane] = a0c0; red[wid][0][1][lane] = a0c1; red[wid][0][2][lane] = a0c2;
    red[wid][1][0][lane] = a1c0; red[wid][1][1][lane] = a1c1; red[wid][1][2][lane] = a1c2;
    red[wid][2][0][lane] = a2c0; red[wid][2][1][lane] = a2c1; red[wid][2][2][lane] = a2c2;
    red[wid][3][0][lane] = a3c0; red[wid][3][1][lane] = a3c1; red[wid][3][2][lane] = a3c2;
    __syncthreads();

    if (wid < 4) {
        const int i = i0 + wid;
        const float* __restrict__ Pb = Ppart + (size_t)b * 16 * 6 * 64;
        float p[3] = {0.f, 0.f, 0.f};
#pragma unroll
        for (int dt = 0; dt < 16; ++dt) {
#pragma unroll
            for (int c = 0; c < 3; ++c) {
                p[c] += Pb[(dt * 6 + c) * 64 + lane];       // P1[j=lane], coalesced
                p[c] += Pb[(dt * 6 + 3 + c) * 64 + i];      // P2[i], uniform
            }
        }
        float* __restrict__ orow = out + (((size_t)(b * KK + i)) * KK + lane) * 3;
#pragma unroll
        for (int c = 0; c < 3; ++c) {
            float s = p[c];
#pragma unroll
            for (int w = 0; w < 8; ++w) s += red[w][wid][c][lane];
            orow[c] = s;
        }
    }
}

extern "C" void kernel_launch(void* const* d_in, const int* in_sizes, int n_in,
                              void* d_out, int out_size, void* d_ws, size_t ws_size,
                              hipStream_t stream)
{
    const float* Mp = (const float*)d_in[0];   // (16, 64, 1024) f32
    // d_in[1] = mask_p: unused by the reference (all-ones, never applied)
    const float* W  = (const float*)d_in[2];   // (3, 4096) f32
    float* out = (float*)d_out;                // (16, 64, 64, 3) f32

    float* MpT2  = (float*)d_ws;
    float* Ppart = MpT2 + PPART_OFF;

    prep2<<<dim3(BSZ, 16), 256, 0, stream>>>(Mp, W, MpT2, Ppart);
    pair3<<<dim3(BSZ, 16), 512, 0, stream>>>(Mp, W, MpT2, Ppart, out);
}